// Round 20
// baseline (75.869 us; speedup 1.0000x reference)
//
#include <hip/hip_runtime.h>

#define NN 10000
#define NE 40000

typedef __attribute__((ext_vector_type(8))) short bf16x8;
typedef __attribute__((ext_vector_type(4))) float f32x4;
typedef __attribute__((ext_vector_type(8))) unsigned short u16x8;

__device__ inline unsigned short bf16rne(float f) {
  union { float f; unsigned u; } v; v.f = f;
  return (unsigned short)((v.u + 0x7FFFu + ((v.u >> 16) & 1u)) >> 16);
}

// ---- setup kernel: blocks 0-255 reorder ew2s, 256/257 reorder ew1s,
// 258..882 zero P1, 883..1195 zero outf. --------------------------------------
__global__ void k_setup(const float* __restrict__ e1w2, const float* __restrict__ e2w2,
                        const float* __restrict__ e1w1, const float* __restrict__ e2w1,
                        unsigned short* __restrict__ B1, unsigned short* __restrict__ B2,
                        unsigned short* __restrict__ B1e, unsigned short* __restrict__ B2e,
                        float* __restrict__ P1, float* __restrict__ outf) {
  const int b = blockIdx.x;
  const int tid = threadIdx.x;
  if (b < 256) {
    const float* ew2 = (b < 128) ? e1w2 : e2w2;
    unsigned short* out = (b < 128) ? B1 : B2;
    const int ct = b & 127;
    const int l = tid & 63, kk = tid >> 6, g = l >> 4;
    const int col = ct * 16 + (l & 15);
    u16x8 v;
#pragma unroll
    for (int j = 0; j < 8; ++j) v[j] = bf16rne(ew2[(kk * 32 + g * 8 + j) * 2048 + col]);
    *reinterpret_cast<u16x8*>(out + ((size_t)(ct * 2048 + kk * 512 + l * 8))) = v;
  } else if (b < 258) {
    const float* ew1 = (b == 256) ? e1w1 : e2w1;
    unsigned short* out = (b == 256) ? B1e : B2e;
    const int l = tid & 63, g = l >> 4;
#pragma unroll
    for (int half = 0; half < 2; ++half) {
      const int ct = (tid >> 6) + half * 4;
      u16x8 v;
#pragma unroll
      for (int j = 0; j < 8; ++j) {
        int k = g * 8 + j;
        v[j] = (k < 16) ? bf16rne(ew1[k * 128 + ct * 16 + (l & 15)]) : (unsigned short)0;
      }
      *reinterpret_cast<u16x8*>(out + ((size_t)(ct * 64 + l) * 8)) = v;
    }
  } else if (b < 258 + 625) {
    f32x4 z = {0.f, 0.f, 0.f, 0.f};
    *reinterpret_cast<f32x4*>(&P1[(size_t)(b - 258) * 1024 + tid * 4]) = z;
  } else {
    const size_t idx = (size_t)(b - 883) * 1024 + tid * 4;
    if (idx + 3 < (size_t)NN * 32) {
      f32x4 z = {0.f, 0.f, 0.f, 0.f};
      *reinterpret_cast<f32x4*>(&outf[idx]) = z;
    } else {
      for (size_t u = idx; u < (size_t)NN * 32; ++u) outf[u] = 0.f;
    }
  }
}

// ---- fused layer kernel: blocks [0, NEB) = edge blocks; rest = root blocks
// (atomicAdd x@root+bias into zeroed aggr, order-free). -----------------------
template <int CI, int CO, bool RELU_IN>
__global__ __launch_bounds__(256, 2) void k_layer(
    const int* __restrict__ src, const int* __restrict__ dst,
    const float* __restrict__ eattr,
    const unsigned short* __restrict__ ew1f, const float* __restrict__ eb1,
    const unsigned short* __restrict__ bfrag, const float* __restrict__ eb2,
    const float* __restrict__ rootw, const float* __restrict__ rootb,
    const float* __restrict__ xin, float* __restrict__ aggr) {
  constexpr int TE = 64;
  constexpr int NEB = NE / TE;  // 625 edge blocks
  const int tid = threadIdx.x;

  if ((int)blockIdx.x >= NEB) {
    const int idx = ((int)blockIdx.x - NEB) * 256 + tid;
    if (idx < NN * CO) {
      const int n = idx / CO, o = idx % CO;
      float acc = rootb[o];
#pragma unroll
      for (int k = 0; k < CI; ++k) {
        float v = xin[(size_t)n * CI + k];
        if (RELU_IN) v = fmaxf(v, 0.f);
        acc += v * rootw[k * CO + o];
      }
      atomicAdd(&aggr[idx], acc);
    }
    return;
  }

  // ---- edge block (R18 config + COMP de-serialization: bb prefetched one
  // iter ahead; xs LDS reads hoisted before the MFMA chains; setprio narrowed)
  const int e0 = blockIdx.x * TE;
  const int toff = blockIdx.x & 31;

  __shared__ int s_src[TE];
  __shared__ int s_dst[TE];
  __shared__ float s_x[CI][68];
  __shared__ unsigned short s_hfrag[16 * 64 * 8];  // 16 KB

  if (tid < TE) { s_src[tid] = src[e0 + tid]; s_dst[tid] = dst[e0 + tid]; }
  __syncthreads();

  for (int idx = tid; idx < TE * CI; idx += 256) {
    int e = idx / CI, c = idx % CI;
    float v = xin[(size_t)s_src[e] * CI + c];
    if (RELU_IN) v = fmaxf(v, 0.f);
    s_x[c][e] = v;
  }

  const int l = tid & 63, w = tid >> 6, g = l >> 4, c16 = l & 15;

  // H phase via MFMA: wave w -> edge tile m=w, all 128 channels
  {
    const int m = w;
    bf16x8 ea;
#pragma unroll
    for (int j = 0; j < 8; ++j) ea[j] = 0;
    if (g < 2) {
      const float* p = eattr + (size_t)(e0 + 16 * m + c16) * 16 + g * 8;
      f32x4 v0 = *reinterpret_cast<const f32x4*>(p);
      f32x4 v1 = *reinterpret_cast<const f32x4*>(p + 4);
#pragma unroll
      for (int j = 0; j < 4; ++j) { ea[j] = bf16rne(v0[j]); ea[4 + j] = bf16rne(v1[j]); }
    }
#pragma unroll
    for (int ct = 0; ct < 8; ++ct) {
      bf16x8 bw = *reinterpret_cast<const bf16x8*>(ew1f + (size_t)(ct * 64 + l) * 8);
      const float bb = eb1[ct * 16 + c16];
      f32x4 acc = {bb, bb, bb, bb};
      acc = __builtin_amdgcn_mfma_f32_16x16x32_bf16(ea, bw, acc, 0, 0, 0);
#pragma unroll
      for (int r = 0; r < 4; ++r) {
        const int c = ct * 16 + c16;
        s_hfrag[(((m * 4) + (c >> 5)) * 64 + ((c >> 3) & 3) * 16 + g * 4 + r) * 8 + (c & 7)] =
            bf16rne(fmaxf(acc[r], 0.f));
      }
    }
  }
  __syncthreads();

  bf16x8 afrag[4][4];
#pragma unroll
  for (int m = 0; m < 4; ++m)
#pragma unroll
    for (int kk = 0; kk < 4; ++kk)
      afrag[m][kk] = *reinterpret_cast<const bf16x8*>(&s_hfrag[((m * 4 + kk) * 64 + l) * 8]);

  float msg[4][4];
#pragma unroll
  for (int m = 0; m < 4; ++m)
#pragma unroll
    for (int r = 0; r < 4; ++r) msg[m][r] = 0.f;

  const int ocol = (CI == 32) ? (w * 16 + c16) : ((w & 1) * 16 + c16);
  const bf16x8* Bb = reinterpret_cast<const bf16x8*>(bfrag);

  bf16x8 bA[4], bB[4];
  float bbA, bbB;

// PREF: 4x b128 B-fragment loads + the NEXT iter's eb2 scalar (off critical path)
#define PREF(T, BUF, BBV)                                                        \
  {                                                                              \
    const int tt_ = ((T) + toff) & 31;                                           \
    const int i_ = (CI == 32) ? tt_ : ((w >> 1) + 2 * tt_);                      \
    const int ct_ = (CI == 32) ? (tt_ * 4 + w) : (i_ * 2 + (w & 1));             \
    const bf16x8* bp_ = Bb + (size_t)ct_ * 256 + l;                              \
    _Pragma("unroll") for (int kk = 0; kk < 4; ++kk) BUF[kk] = bp_[kk * 64];     \
    BBV = eb2[i_ * CO + ocol];                                                   \
  }

// COMP: xs LDS reads issued FIRST (latency hides under MFMA issue), then the
// pure-MFMA cluster under setprio, then the epilogue using pre-loaded xs/bb.
#define COMP(T, BUF, BBV)                                                        \
  {                                                                              \
    const int tt_ = ((T) + toff) & 31;                                           \
    const int i_ = (CI == 32) ? tt_ : ((w >> 1) + 2 * tt_);                      \
    f32x4 xs[4];                                                                 \
    _Pragma("unroll") for (int m = 0; m < 4; ++m)                                \
        xs[m] = *reinterpret_cast<const f32x4*>(&s_x[i_][m * 16 + g * 4]);       \
    f32x4 wacc[4];                                                               \
    __builtin_amdgcn_s_setprio(1);                                               \
    _Pragma("unroll") for (int m = 0; m < 4; ++m) {                              \
      f32x4 a_ = {0.f, 0.f, 0.f, 0.f};                                           \
      _Pragma("unroll") for (int kk = 0; kk < 4; ++kk)                           \
          a_ = __builtin_amdgcn_mfma_f32_16x16x32_bf16(afrag[m][kk], BUF[kk],    \
                                                       a_, 0, 0, 0);             \
      wacc[m] = a_;                                                              \
    }                                                                            \
    __builtin_amdgcn_s_setprio(0);                                               \
    _Pragma("unroll") for (int m = 0; m < 4; ++m)                                \
      _Pragma("unroll") for (int r = 0; r < 4; ++r)                              \
          msg[m][r] += fmaxf(wacc[m][r] + BBV, 0.f) * xs[m][r];                  \
  }

  PREF(0, bA, bbA)
#pragma unroll 1
  for (int t = 0; t < 30; t += 2) {
    PREF(t + 1, bB, bbB)
    COMP(t, bA, bbA)
    PREF(t + 2, bA, bbA)
    COMP(t + 1, bB, bbB)
  }
  PREF(31, bB, bbB)
  COMP(30, bA, bbA)
  COMP(31, bB, bbB)
#undef PREF
#undef COMP

  // coalesced atomics: per instruction, 4 edges x 16 consecutive cols (64B runs)
#pragma unroll
  for (int m = 0; m < 4; ++m)
#pragma unroll
    for (int r = 0; r < 4; ++r)
      atomicAdd(&aggr[(size_t)s_dst[m * 16 + g * 4 + r] * CO + ocol], msg[m][r]);
}

extern "C" void kernel_launch(void* const* d_in, const int* in_sizes, int n_in,
                              void* d_out, int out_size, void* d_ws, size_t ws_size,
                              hipStream_t stream) {
  const float* x       = (const float*)d_in[0];
  const int*   ei      = (const int*)d_in[1];
  const float* eattr   = (const float*)d_in[2];
  const float* l1_ew1  = (const float*)d_in[3];
  const float* l1_eb1  = (const float*)d_in[4];
  const float* l1_ew2  = (const float*)d_in[5];
  const float* l1_eb2  = (const float*)d_in[6];
  const float* l1_root = (const float*)d_in[7];
  const float* l1_bias = (const float*)d_in[8];
  const float* l2_ew1  = (const float*)d_in[9];
  const float* l2_eb1  = (const float*)d_in[10];
  const float* l2_ew2  = (const float*)d_in[11];
  const float* l2_eb2  = (const float*)d_in[12];
  const float* l2_root = (const float*)d_in[13];
  const float* l2_bias = (const float*)d_in[14];

  const int* src = ei;
  const int* dst = ei + NE;

  char* ws = (char*)d_ws;
  float* P1 = (float*)ws;                                  // 2,560,000 B
  unsigned short* B1  = (unsigned short*)(ws + 2560000);   // 524,288 B
  unsigned short* B2  = (unsigned short*)(ws + 3084288);   // 524,288 B
  unsigned short* B1e = (unsigned short*)(ws + 3608576);   // 8,192 B
  unsigned short* B2e = (unsigned short*)(ws + 3616768);   // 8,192 B
  float* outf = (float*)d_out;

  k_setup<<<1196, 256, 0, stream>>>(l1_ew2, l2_ew2, l1_ew1, l2_ew1,
                                    B1, B2, B1e, B2e, P1, outf);
  k_layer<32, 64, false><<<NE / 64 + (NN * 64 + 255) / 256, 256, 0, stream>>>(
      src, dst, eattr, B1e, l1_eb1, B1, l1_eb2, l1_root, l1_bias, x, P1);
  k_layer<64, 32, true><<<NE / 64 + (NN * 32 + 255) / 256, 256, 0, stream>>>(
      src, dst, eattr, B2e, l2_eb1, B2, l2_eb2, l2_root, l2_bias, P1, outf);
}

// Round 21
// 70.151 us; speedup vs baseline: 1.0815x; 1.0815x over previous
//
#include <hip/hip_runtime.h>

#define NN 10000
#define NE 40000

typedef __attribute__((ext_vector_type(8))) short bf16x8;
typedef __attribute__((ext_vector_type(4))) float f32x4;
typedef __attribute__((ext_vector_type(8))) unsigned short u16x8;

__device__ inline unsigned short bf16rne(float f) {
  union { float f; unsigned u; } v; v.f = f;
  return (unsigned short)((v.u + 0x7FFFu + ((v.u >> 16) & 1u)) >> 16);
}

// ---- setup kernel: blocks 0-255 reorder ew2s, 256/257 reorder ew1s,
// 258..882 zero P1, 883..1195 zero outf. --------------------------------------
__global__ void k_setup(const float* __restrict__ e1w2, const float* __restrict__ e2w2,
                        const float* __restrict__ e1w1, const float* __restrict__ e2w1,
                        unsigned short* __restrict__ B1, unsigned short* __restrict__ B2,
                        unsigned short* __restrict__ B1e, unsigned short* __restrict__ B2e,
                        float* __restrict__ P1, float* __restrict__ outf) {
  const int b = blockIdx.x;
  const int tid = threadIdx.x;
  if (b < 256) {
    // ew2 reorder: elem j of lane l, col-tile ct, k-chunk kk =
    // B[kk*32+(l>>4)*8+j][ct*16+(l&15)] at ushort idx ct*2048+kk*512+l*8+j.
    const float* ew2 = (b < 128) ? e1w2 : e2w2;
    unsigned short* out = (b < 128) ? B1 : B2;
    const int ct = b & 127;
    const int l = tid & 63, kk = tid >> 6, g = l >> 4;
    const int col = ct * 16 + (l & 15);
    u16x8 v;
#pragma unroll
    for (int j = 0; j < 8; ++j) v[j] = bf16rne(ew2[(kk * 32 + g * 8 + j) * 2048 + col]);
    *reinterpret_cast<u16x8*>(out + ((size_t)(ct * 2048 + kk * 512 + l * 8))) = v;
  } else if (b < 258) {
    // ew1 [16 x 128] -> bf16 B-frag, K padded to 32 with zeros; 8 col-tiles.
    const float* ew1 = (b == 256) ? e1w1 : e2w1;
    unsigned short* out = (b == 256) ? B1e : B2e;
    const int l = tid & 63, g = l >> 4;
#pragma unroll
    for (int half = 0; half < 2; ++half) {
      const int ct = (tid >> 6) + half * 4;
      u16x8 v;
#pragma unroll
      for (int j = 0; j < 8; ++j) {
        int k = g * 8 + j;
        v[j] = (k < 16) ? bf16rne(ew1[k * 128 + ct * 16 + (l & 15)]) : (unsigned short)0;
      }
      *reinterpret_cast<u16x8*>(out + ((size_t)(ct * 64 + l) * 8)) = v;
    }
  } else if (b < 258 + 625) {
    // zero P1 (NN*64 = 640000 f32, exact)
    f32x4 z = {0.f, 0.f, 0.f, 0.f};
    *reinterpret_cast<f32x4*>(&P1[(size_t)(b - 258) * 1024 + tid * 4]) = z;
  } else {
    // zero outf (NN*32 = 320000 f32, guarded tail)
    const size_t idx = (size_t)(b - 883) * 1024 + tid * 4;
    if (idx + 3 < (size_t)NN * 32) {
      f32x4 z = {0.f, 0.f, 0.f, 0.f};
      *reinterpret_cast<f32x4*>(&outf[idx]) = z;
    } else {
      for (size_t u = idx; u < (size_t)NN * 32; ++u) outf[u] = 0.f;
    }
  }
}

// ---- fused layer kernel: blocks [0, NEB) = edge blocks (R18 body);
// blocks [NEB, ...) = root blocks, atomicAdd x@root+bias into zeroed aggr. ----
template <int CI, int CO, bool RELU_IN>
__global__ __launch_bounds__(256, 2) void k_layer(
    const int* __restrict__ src, const int* __restrict__ dst,
    const float* __restrict__ eattr,
    const unsigned short* __restrict__ ew1f, const float* __restrict__ eb1,
    const unsigned short* __restrict__ bfrag, const float* __restrict__ eb2,
    const float* __restrict__ rootw, const float* __restrict__ rootb,
    const float* __restrict__ xin, float* __restrict__ aggr) {
  constexpr int TE = 64;
  constexpr int NEB = NE / TE;  // 625 edge blocks
  const int tid = threadIdx.x;

  if ((int)blockIdx.x >= NEB) {
    // ---- root block: out[n,o] += bias[o] + sum_k relu?(xin[n,k]) * root[k,o]
    const int idx = ((int)blockIdx.x - NEB) * 256 + tid;
    if (idx < NN * CO) {
      const int n = idx / CO, o = idx % CO;
      float acc = rootb[o];
#pragma unroll
      for (int k = 0; k < CI; ++k) {
        float v = xin[(size_t)n * CI + k];
        if (RELU_IN) v = fmaxf(v, 0.f);
        acc += v * rootw[k * CO + o];
      }
      atomicAdd(&aggr[idx], acc);
    }
    return;
  }

  // ---- edge block (R18 configuration: depth-2 reg prefetch, t-stagger,
  // H via MFMA, setprio around MFMA cluster, coalesced atomics)
  const int e0 = blockIdx.x * TE;
  const int toff = blockIdx.x & 31;

  __shared__ int s_src[TE];
  __shared__ int s_dst[TE];
  __shared__ float s_x[CI][68];
  __shared__ unsigned short s_hfrag[16 * 64 * 8];  // 16 KB

  if (tid < TE) { s_src[tid] = src[e0 + tid]; s_dst[tid] = dst[e0 + tid]; }
  __syncthreads();

  for (int idx = tid; idx < TE * CI; idx += 256) {
    int e = idx / CI, c = idx % CI;
    float v = xin[(size_t)s_src[e] * CI + c];
    if (RELU_IN) v = fmaxf(v, 0.f);
    s_x[c][e] = v;
  }

  const int l = tid & 63, w = tid >> 6, g = l >> 4, c16 = l & 15;

  // H phase via MFMA: wave w -> edge tile m=w, all 128 channels
  {
    const int m = w;
    bf16x8 ea;
#pragma unroll
    for (int j = 0; j < 8; ++j) ea[j] = 0;
    if (g < 2) {
      const float* p = eattr + (size_t)(e0 + 16 * m + c16) * 16 + g * 8;
      f32x4 v0 = *reinterpret_cast<const f32x4*>(p);
      f32x4 v1 = *reinterpret_cast<const f32x4*>(p + 4);
#pragma unroll
      for (int j = 0; j < 4; ++j) { ea[j] = bf16rne(v0[j]); ea[4 + j] = bf16rne(v1[j]); }
    }
#pragma unroll
    for (int ct = 0; ct < 8; ++ct) {
      bf16x8 bw = *reinterpret_cast<const bf16x8*>(ew1f + (size_t)(ct * 64 + l) * 8);
      const float bb = eb1[ct * 16 + c16];
      f32x4 acc = {bb, bb, bb, bb};
      acc = __builtin_amdgcn_mfma_f32_16x16x32_bf16(ea, bw, acc, 0, 0, 0);
#pragma unroll
      for (int r = 0; r < 4; ++r) {
        const int c = ct * 16 + c16;
        s_hfrag[(((m * 4) + (c >> 5)) * 64 + ((c >> 3) & 3) * 16 + g * 4 + r) * 8 + (c & 7)] =
            bf16rne(fmaxf(acc[r], 0.f));
      }
    }
  }
  __syncthreads();

  bf16x8 afrag[4][4];
#pragma unroll
  for (int m = 0; m < 4; ++m)
#pragma unroll
    for (int kk = 0; kk < 4; ++kk)
      afrag[m][kk] = *reinterpret_cast<const bf16x8*>(&s_hfrag[((m * 4 + kk) * 64 + l) * 8]);

  float msg[4][4];
#pragma unroll
  for (int m = 0; m < 4; ++m)
#pragma unroll
    for (int r = 0; r < 4; ++r) msg[m][r] = 0.f;

  const int ocol = (CI == 32) ? (w * 16 + c16) : ((w & 1) * 16 + c16);
  const bf16x8* Bb = reinterpret_cast<const bf16x8*>(bfrag);

  bf16x8 bA[4], bB[4];

#define PREF(T, BUF)                                                             \
  {                                                                              \
    const int tt_ = ((T) + toff) & 31;                                           \
    const int i_ = (CI == 32) ? tt_ : ((w >> 1) + 2 * tt_);                      \
    const int ct_ = (CI == 32) ? (tt_ * 4 + w) : (i_ * 2 + (w & 1));             \
    const bf16x8* bp_ = Bb + (size_t)ct_ * 256 + l;                              \
    _Pragma("unroll") for (int kk = 0; kk < 4; ++kk) BUF[kk] = bp_[kk * 64];     \
  }

#define COMP(T, BUF)                                                             \
  {                                                                              \
    const int tt_ = ((T) + toff) & 31;                                           \
    const int i_ = (CI == 32) ? tt_ : ((w >> 1) + 2 * tt_);                      \
    const float bb = eb2[i_ * CO + ocol];                                        \
    __builtin_amdgcn_s_setprio(1);                                               \
    _Pragma("unroll") for (int m = 0; m < 4; ++m) {                              \
      f32x4 wacc = {0.f, 0.f, 0.f, 0.f};                                         \
      _Pragma("unroll") for (int kk = 0; kk < 4; ++kk)                           \
          wacc = __builtin_amdgcn_mfma_f32_16x16x32_bf16(afrag[m][kk], BUF[kk],  \
                                                         wacc, 0, 0, 0);         \
      const f32x4 xs = *reinterpret_cast<const f32x4*>(&s_x[i_][m * 16 + g * 4]);\
      _Pragma("unroll") for (int r = 0; r < 4; ++r)                              \
          msg[m][r] += fmaxf(wacc[r] + bb, 0.f) * xs[r];                         \
    }                                                                            \
    __builtin_amdgcn_s_setprio(0);                                               \
  }

  PREF(0, bA)
#pragma unroll 1
  for (int t = 0; t < 30; t += 2) {
    PREF(t + 1, bB)
    COMP(t, bA)
    PREF(t + 2, bA)
    COMP(t + 1, bB)
  }
  PREF(31, bB)
  COMP(30, bA)
  COMP(31, bB)
#undef PREF
#undef COMP

  // coalesced atomics: per instruction, 4 edges x 16 consecutive cols (64B runs)
#pragma unroll
  for (int m = 0; m < 4; ++m)
#pragma unroll
    for (int r = 0; r < 4; ++r)
      atomicAdd(&aggr[(size_t)s_dst[m * 16 + g * 4 + r] * CO + ocol], msg[m][r]);
}

extern "C" void kernel_launch(void* const* d_in, const int* in_sizes, int n_in,
                              void* d_out, int out_size, void* d_ws, size_t ws_size,
                              hipStream_t stream) {
  const float* x       = (const float*)d_in[0];
  const int*   ei      = (const int*)d_in[1];
  const float* eattr   = (const float*)d_in[2];
  const float* l1_ew1  = (const float*)d_in[3];
  const float* l1_eb1  = (const float*)d_in[4];
  const float* l1_ew2  = (const float*)d_in[5];
  const float* l1_eb2  = (const float*)d_in[6];
  const float* l1_root = (const float*)d_in[7];
  const float* l1_bias = (const float*)d_in[8];
  const float* l2_ew1  = (const float*)d_in[9];
  const float* l2_eb1  = (const float*)d_in[10];
  const float* l2_ew2  = (const float*)d_in[11];
  const float* l2_eb2  = (const float*)d_in[12];
  const float* l2_root = (const float*)d_in[13];
  const float* l2_bias = (const float*)d_in[14];

  const int* src = ei;
  const int* dst = ei + NE;

  char* ws = (char*)d_ws;
  float* P1 = (float*)ws;                                  // 2,560,000 B
  unsigned short* B1  = (unsigned short*)(ws + 2560000);   // 524,288 B
  unsigned short* B2  = (unsigned short*)(ws + 3084288);   // 524,288 B
  unsigned short* B1e = (unsigned short*)(ws + 3608576);   // 8,192 B
  unsigned short* B2e = (unsigned short*)(ws + 3616768);   // 8,192 B
  float* outf = (float*)d_out;

  // L1: reorders + zero P1 + zero outf (all independent)
  k_setup<<<1196, 256, 0, stream>>>(l1_ew2, l2_ew2, l1_ew1, l2_ew1,
                                    B1, B2, B1e, B2e, P1, outf);
  // L2: edge blocks + root blocks, order-free atomic accumulation into P1
  k_layer<32, 64, false><<<NE / 64 + (NN * 64 + 255) / 256, 256, 0, stream>>>(
      src, dst, eattr, B1e, l1_eb1, B1, l1_eb2, l1_root, l1_bias, x, P1);
  // L3: same for layer 2 into outf (reads pre-relu P1, applies relu on read)
  k_layer<64, 32, true><<<NE / 64 + (NN * 32 + 255) / 256, 256, 0, stream>>>(
      src, dst, eattr, B2e, l2_eb1, B2, l2_eb2, l2_root, l2_bias, P1, outf);
}